// Round 6
// baseline (1896.820 us; speedup 1.0000x reference)
//
#include <hip/hip_runtime.h>
#include <hip/hip_bf16.h>

// Additive coupling forward via split-bf16 MFMA (Ah*Bh + Ah*Bl + Al*Bh).
// Round 4 (2nd resubmit): gemm8 inner loop restructured into the m201-style
// 2-phase-per-K-tile schedule: raw s_barrier + explicit s_waitcnt fences +
// setprio MFMA windows, with phase-1 A-fragment reads overlapped under
// phase-0's MFMA cluster. Everything else unchanged.
//
// Packed format for matrix X (R x K):  Xp[((r*K/32 + kt))*64 + pos*8 + e]
//   element (r,k): kt=k>>5, chunk c=(k&31)>>3 (hi) or 4+((k&31)>>3) (lo),
//   e=k&7, stored chunk position pos = c ^ (r&7).
// Row image = the swizzled LDS image -> global_load_lds copies 128B rows
// linearly; reads XOR with row&7; 128B row stride = full bank wrap ->
// conflict-free (measured: SQ_LDS_BANK_CONFLICT == 0).

#define B_DIM    4096
#define D_DIM    2048
#define HALF_DIM 1024
#define MID_DIM  4096
#define NHID     4

typedef __attribute__((ext_vector_type(8))) short frag_ab;   // 8 bf16
typedef __attribute__((ext_vector_type(4))) float frag_cd;   // 4 f32

#define GAS __attribute__((address_space(1)))
#define LAS __attribute__((address_space(3)))

__device__ __forceinline__ ushort f2bf_rtn(float v) {
    unsigned u = __builtin_bit_cast(unsigned, v);
    unsigned r = u + 0x7FFFu + ((u >> 16) & 1u);
    return (ushort)(r >> 16);
}
__device__ __forceinline__ void split_hilo(float v, ushort& h, ushort& l) {
    h = f2bf_rtn(v);
    float fh = __builtin_bit_cast(float, (unsigned)h << 16);
    l = f2bf_rtn(v - fh);
}

// ---------------------------------------------------------------------------
// prep: x2 = x[:, 2c+1] -> packed-swizzled bf16 hi/lo; forward log_det_J.
__global__ __launch_bounds__(256) void prep_x2(const float* __restrict__ x,
                                               const float* __restrict__ logd,
                                               ushort* __restrict__ x2p,
                                               float* __restrict__ outLog) {
    int idx = blockIdx.x * 256 + threadIdx.x;        // 0 .. B*HALF-1
    if (idx == 0) outLog[0] = logd[0];
    int b = idx >> 10, c = idx & 1023;
    float2 v = ((const float2*)x)[idx];              // (x[b][2c], x[b][2c+1])
    ushort h, l; split_hilo(v.y, h, l);
    int kt = c >> 5, w = c & 31;
    int pos = (w >> 3) ^ (b & 7);
    size_t base = ((size_t)(b * 32 + kt)) * 64 + (w & 7);   // PK = 1024/32 = 32
    x2p[base + pos * 8]       = h;
    x2p[base + (pos ^ 4) * 8] = l;
}

// ---------------------------------------------------------------------------
// transpose + split: in (K x N) f32 row-major -> packed-swizzled (N rows, K).
__global__ __launch_bounds__(256) void transpose_split(const float* __restrict__ in,
                                                       int K, int N,
                                                       ushort* __restrict__ outP) {
    __shared__ float tile[64][65];
    const int n0 = blockIdx.x * 64, k0 = blockIdx.y * 64;
    const int t = threadIdx.x;
    const int c = t & 63, g = t >> 6;
#pragma unroll
    for (int r = 0; r < 16; ++r)
        tile[g * 16 + r][c] = in[(size_t)(k0 + g * 16 + r) * N + n0 + c];
    __syncthreads();
    const int PK = K >> 5;
#pragma unroll
    for (int r = 0; r < 16; ++r) {
        int nrow = g * 16 + r;
        float v = tile[c][nrow];                     // = in[k0+c][n0+nrow]
        int n = n0 + nrow, k = k0 + c;
        ushort h, l; split_hilo(v, h, l);
        int kt = k >> 5, w = k & 31;
        int pos = (w >> 3) ^ (n & 7);
        size_t base = ((size_t)n * PK + kt) * 64 + (w & 7);
        outP[base + pos * 8]       = h;
        outP[base + (pos ^ 4) * 8] = l;
    }
}

// ---------------------------------------------------------------------------
// gemm8: 256x256 tile, 8 waves (2Mx4N), BK=32, 2-phase schedule per K-tile.
__global__ __launch_bounds__(512, 2) void gemm8(
    const ushort* __restrict__ Ap, const ushort* __restrict__ Bp,
    const float* __restrict__ bias, int K, int N,
    ushort* __restrict__ Cp) {
    __shared__ ushort sA[2][16384];                  // 2 x 256 x 64  (64 KB)
    __shared__ ushort sB[2][16384];                  // 64 KB
    const int t = threadIdx.x;
    const int w = t >> 6, l = t & 63;
    const int bid = blockIdx.x;
    const int swz = (bid & 7) * 32 + (bid >> 3);     // bijective (256 % 8 == 0)
    const int bx = swz & 15, by = swz >> 4;          // N/256 = 16
    const int m0 = by * 256, n0 = bx * 256;
    const int wr = w >> 2, wc = w & 3;               // wave 128x64 output
    const int lr = l & 15, lc = l >> 4;              // lc = 0..3
    const int PK = K >> 5, NK = PK;

    // staging: thread t -> row t>>3 (of 64/call), chunk t&7 (16B)
    const ushort* aSrc = Ap + (size_t)(m0 + (t >> 3)) * (PK * 64) + (t & 7) * 8;
    const ushort* bSrc = Bp + (size_t)(n0 + (t >> 3)) * (PK * 64) + (t & 7) * 8;
    const size_t qstep = (size_t)64 * PK * 64;       // 64 rows
    const int ldsBase = w * 512;                     // + q*4096; HW adds lane*16B

#define STAGE_AB(buf, kt) do {                                                       \
    const ushort* _as = aSrc + (size_t)(kt) * 64;                                    \
    const ushort* _bs = bSrc + (size_t)(kt) * 64;                                    \
    _Pragma("unroll")                                                                \
    for (int q = 0; q < 4; ++q) {                                                    \
        __builtin_amdgcn_global_load_lds((const GAS void*)(_as + q * qstep),         \
                                         (LAS void*)&sA[buf][q * 4096 + ldsBase], 16, 0, 0); \
        __builtin_amdgcn_global_load_lds((const GAS void*)(_bs + q * qstep),         \
                                         (LAS void*)&sB[buf][q * 4096 + ldsBase], 16, 0, 0); \
    } } while (0)

    frag_cd acc[8][4];
#pragma unroll
    for (int i = 0; i < 8; ++i)
#pragma unroll
        for (int j = 0; j < 4; ++j) acc[i][j] = (frag_cd){0.f, 0.f, 0.f, 0.f};

    float bv[4];
#pragma unroll
    for (int j = 0; j < 4; ++j) bv[j] = bias[n0 + wc * 64 + j * 16 + lr];

    STAGE_AB(0, 0);                                  // prologue: tile 0
    for (int kt = 0; kt < NK; ++kt) {
        const int cur = kt & 1;
        // ---- opening: all staging for tile kt landed (lead >= 1 full tile)
        asm volatile("s_waitcnt vmcnt(0)" ::: "memory");
        __builtin_amdgcn_s_barrier();
        // prefetch tile kt+1 into the other buffer (safe: every wave passed
        // the barrier, so all reads of buf cur^1 from tile kt-1 are complete)
        if (kt + 1 < NK) STAGE_AB(cur ^ 1, kt + 1);

        // ---- phase 0: B frags + A frags (mh=0)
        frag_ab fbh[4], fbl[4];
#pragma unroll
        for (int j = 0; j < 4; ++j) {
            int row = wc * 64 + j * 16 + lr;
            int ph = lc ^ (row & 7);
            fbh[j] = *(const frag_ab*)&sB[cur][row * 64 + ph * 8];
            fbl[j] = *(const frag_ab*)&sB[cur][row * 64 + (ph ^ 4) * 8];
        }
        frag_ab fah0[4], fal0[4];
#pragma unroll
        for (int i = 0; i < 4; ++i) {
            int row = wr * 128 + i * 16 + lr;
            int ph = lc ^ (row & 7);
            fah0[i] = *(const frag_ab*)&sA[cur][row * 64 + ph * 8];
            fal0[i] = *(const frag_ab*)&sA[cur][row * 64 + (ph ^ 4) * 8];
        }
        asm volatile("s_waitcnt lgkmcnt(0)" ::: "memory");
        __builtin_amdgcn_sched_barrier(0);
        __builtin_amdgcn_s_setprio(1);
#pragma unroll
        for (int i = 0; i < 4; ++i)
#pragma unroll
            for (int j = 0; j < 4; ++j) {
                acc[i][j] = __builtin_amdgcn_mfma_f32_16x16x32_bf16(fah0[i], fbh[j], acc[i][j], 0, 0, 0);
                acc[i][j] = __builtin_amdgcn_mfma_f32_16x16x32_bf16(fah0[i], fbl[j], acc[i][j], 0, 0, 0);
                acc[i][j] = __builtin_amdgcn_mfma_f32_16x16x32_bf16(fal0[i], fbh[j], acc[i][j], 0, 0, 0);
            }
        __builtin_amdgcn_s_setprio(0);

        // phase-1 A frags issued here: scheduler interleaves their ds_reads
        // under the tail of the MFMA cluster above (no fence in between).
        frag_ab fah1[4], fal1[4];
#pragma unroll
        for (int i = 0; i < 4; ++i) {
            int row = wr * 128 + 64 + i * 16 + lr;
            int ph = lc ^ (row & 7);
            fah1[i] = *(const frag_ab*)&sA[cur][row * 64 + ph * 8];
            fal1[i] = *(const frag_ab*)&sA[cur][row * 64 + (ph ^ 4) * 8];
        }
        __builtin_amdgcn_s_barrier();                // mid-phase stagger point
        asm volatile("s_waitcnt lgkmcnt(0)" ::: "memory");
        __builtin_amdgcn_sched_barrier(0);
        __builtin_amdgcn_s_setprio(1);
#pragma unroll
        for (int i = 0; i < 4; ++i)
#pragma unroll
            for (int j = 0; j < 4; ++j) {
                acc[4 + i][j] = __builtin_amdgcn_mfma_f32_16x16x32_bf16(fah1[i], fbh[j], acc[4 + i][j], 0, 0, 0);
                acc[4 + i][j] = __builtin_amdgcn_mfma_f32_16x16x32_bf16(fah1[i], fbl[j], acc[4 + i][j], 0, 0, 0);
                acc[4 + i][j] = __builtin_amdgcn_mfma_f32_16x16x32_bf16(fal1[i], fbh[j], acc[4 + i][j], 0, 0, 0);
            }
        __builtin_amdgcn_s_setprio(0);
    }
#undef STAGE_AB

    // epilogue: C/D col = lane&15, row = (lane>>4)*4 + reg
    const int PKo = N >> 5;
#pragma unroll
    for (int i = 0; i < 8; ++i) {
#pragma unroll
        for (int j = 0; j < 4; ++j) {
            const int col = n0 + wc * 64 + j * 16 + lr;
            const int kto = col >> 5, w32 = col & 31;
            const int e = w32 & 7, ch = w32 >> 3;
#pragma unroll
            for (int r = 0; r < 4; ++r) {
                const int row = m0 + wr * 128 + i * 16 + lc * 4 + r;
                float v = fmaxf(acc[i][j][r] + bv[j], 0.0f);
                ushort h, lo16; split_hilo(v, h, lo16);
                const int pos = ch ^ (row & 7);
                size_t basec = ((size_t)row * PKo + kto) * 64 + e;
                Cp[basec + pos * 8]       = h;
                Cp[basec + (pos ^ 4) * 8] = lo16;
            }
        }
    }
}

// ---------------------------------------------------------------------------
// gemm2: 128x128 tile, 4 waves, single-barrier pipeline (unchanged, proven);
// epilogue fuses x-add + interleave. Used for L5 (N=1024): grid 256 blocks.
__global__ __launch_bounds__(256, 2) void gemm2(
    const ushort* __restrict__ Ap, const ushort* __restrict__ Bp,
    const float* __restrict__ bias, int K, int N,
    const float* __restrict__ xin, float* __restrict__ yout) {
    __shared__ ushort sA[2][8192];                   // 2 x 128 x 64 (32 KB)
    __shared__ ushort sB[2][8192];
    const int t = threadIdx.x;
    const int w = t >> 6, l = t & 63;
    const int bid = blockIdx.x;
    const int swz = (bid & 7) * 32 + (bid >> 3);
    const int bx = swz & 7, by = swz >> 3;           // N/128 = 8, M/128 = 32
    const int m0 = by * 128, n0 = bx * 128;
    const int wr = w >> 1, wc = w & 1;               // wave 64x64 output
    const int lr = l & 15, lc = l >> 4;
    const int PK = K >> 5, NK = PK;

    const ushort* aSrc = Ap + (size_t)(m0 + (t >> 3)) * (PK * 64) + (t & 7) * 8;
    const ushort* bSrc = Bp + (size_t)(n0 + (t >> 3)) * (PK * 64) + (t & 7) * 8;
    const size_t qstep = (size_t)32 * PK * 64;       // 32 rows / call
    const int ldsBase = w * 512;                     // + q*2048

#define STAGE2(buf, kt) do {                                                         \
    const ushort* _as = aSrc + (size_t)(kt) * 64;                                    \
    const ushort* _bs = bSrc + (size_t)(kt) * 64;                                    \
    _Pragma("unroll")                                                                \
    for (int q = 0; q < 4; ++q) {                                                    \
        __builtin_amdgcn_global_load_lds((const GAS void*)(_as + q * qstep),         \
                                         (LAS void*)&sA[buf][q * 2048 + ldsBase], 16, 0, 0); \
        __builtin_amdgcn_global_load_lds((const GAS void*)(_bs + q * qstep),         \
                                         (LAS void*)&sB[buf][q * 2048 + ldsBase], 16, 0, 0); \
    } } while (0)

    frag_cd acc[4][4];
#pragma unroll
    for (int i = 0; i < 4; ++i)
#pragma unroll
        for (int j = 0; j < 4; ++j) acc[i][j] = (frag_cd){0.f, 0.f, 0.f, 0.f};

    float bv[4];
#pragma unroll
    for (int j = 0; j < 4; ++j) bv[j] = bias[n0 + wc * 64 + j * 16 + lr];

    STAGE2(0, 0);
    for (int kt = 0; kt < NK; ++kt) {
        const int cur = kt & 1;
        __syncthreads();
        if (kt + 1 < NK) STAGE2(cur ^ 1, kt + 1);

        frag_ab fah[4], fal[4], fbh[4], fbl[4];
#pragma unroll
        for (int i = 0; i < 4; ++i) {
            int rowa = wr * 64 + i * 16 + lr;
            int pa = lc ^ (rowa & 7);
            fah[i] = *(const frag_ab*)&sA[cur][rowa * 64 + pa * 8];
            fal[i] = *(const frag_ab*)&sA[cur][rowa * 64 + (pa ^ 4) * 8];
            int rowb = wc * 64 + i * 16 + lr;
            int pb = lc ^ (rowb & 7);
            fbh[i] = *(const frag_ab*)&sB[cur][rowb * 64 + pb * 8];
            fbl[i] = *(const frag_ab*)&sB[cur][rowb * 64 + (pb ^ 4) * 8];
        }
        __builtin_amdgcn_s_setprio(1);
#pragma unroll
        for (int i = 0; i < 4; ++i)
#pragma unroll
            for (int j = 0; j < 4; ++j) {
                acc[i][j] = __builtin_amdgcn_mfma_f32_16x16x32_bf16(fah[i], fbh[j], acc[i][j], 0, 0, 0);
                acc[i][j] = __builtin_amdgcn_mfma_f32_16x16x32_bf16(fah[i], fbl[j], acc[i][j], 0, 0, 0);
                acc[i][j] = __builtin_amdgcn_mfma_f32_16x16x32_bf16(fal[i], fbh[j], acc[i][j], 0, 0, 0);
            }
        __builtin_amdgcn_s_setprio(0);
    }
#undef STAGE2

    // epilogue: y[row][2c] = x[row][2c] + (acc+bias); y[row][2c+1] = x[row][2c+1]
#pragma unroll
    for (int i = 0; i < 4; ++i) {
#pragma unroll
        for (int j = 0; j < 4; ++j) {
            const int col = n0 + wc * 64 + j * 16 + lr;
#pragma unroll
            for (int r = 0; r < 4; ++r) {
                const int row = m0 + wr * 64 + i * 16 + lc * 4 + r;
                float v = acc[i][j][r] + bv[j];
                const float2 xv = ((const float2*)xin)[(size_t)row * (D_DIM / 2) + col];
                float2 yv; yv.x = xv.x + v; yv.y = xv.y;
                ((float2*)yout)[(size_t)row * (D_DIM / 2) + col] = yv;
            }
        }
    }
}

// ---------------------------------------------------------------------------
extern "C" void kernel_launch(void* const* d_in, const int* in_sizes, int n_in,
                              void* d_out, int out_size, void* d_ws, size_t ws_size,
                              hipStream_t stream) {
    const float* x     = (const float*)d_in[0];
    const float* logd  = (const float*)d_in[1];
    const float* W_in  = (const float*)d_in[2];
    const float* b_in  = (const float*)d_in[3];
    const float* W_h   = (const float*)d_in[4];
    const float* b_h   = (const float*)d_in[5];
    const float* W_out = (const float*)d_in[6];
    const float* b_out = (const float*)d_in[7];
    float* y = (float*)d_out;

    // workspace layout (208 MB): x2p 16MB | Wp 64MB | h0 64MB | h1 64MB
    char* ws = (char*)d_ws;
    ushort* x2p = (ushort*)(ws);
    ushort* wp  = (ushort*)(ws + (size_t)16  * (1 << 20));
    ushort* h0  = (ushort*)(ws + (size_t)80  * (1 << 20));
    ushort* h1  = (ushort*)(ws + (size_t)144 * (1 << 20));

    prep_x2<<<dim3(B_DIM * HALF_DIM / 256), 256, 0, stream>>>(
        x, logd, x2p, y + (size_t)B_DIM * D_DIM);

    // L0: h0 = relu(x2 @ W_in + b_in)   (K=1024, N=4096)
    transpose_split<<<dim3(MID_DIM / 64, HALF_DIM / 64), 256, 0, stream>>>(
        W_in, HALF_DIM, MID_DIM, wp);
    gemm8<<<dim3(256), 512, 0, stream>>>(x2p, wp, b_in, HALF_DIM, MID_DIM, h0);

    // L1..L4: h = relu(h @ W_h[i] + b_h[i])  (4096^3)
    ushort *ah = h0, *ch = h1;
    for (int i = 0; i < NHID; ++i) {
        transpose_split<<<dim3(MID_DIM / 64, MID_DIM / 64), 256, 0, stream>>>(
            W_h + (size_t)i * MID_DIM * MID_DIM, MID_DIM, MID_DIM, wp);
        gemm8<<<dim3(256), 512, 0, stream>>>(ah, wp, b_h + (size_t)i * MID_DIM,
                                             MID_DIM, MID_DIM, ch);
        ushort* tmp = ah; ah = ch; ch = tmp;
    }

    // L5: y_even = x_even + (h @ W_out + b_out); y_odd = x_odd  (K=4096, N=1024)
    transpose_split<<<dim3(HALF_DIM / 64, MID_DIM / 64), 256, 0, stream>>>(
        W_out, MID_DIM, HALF_DIM, wp);
    gemm2<<<dim3(256), 256, 0, stream>>>(ah, wp, b_out, MID_DIM, HALF_DIM, x, y);

    (void)in_sizes; (void)n_in; (void)out_size; (void)ws_size;
}